// Round 2
// baseline (1478.172 us; speedup 1.0000x reference)
//
#include <hip/hip_runtime.h>

// LocalConvolution: out[b,o,i,j] = sum_{c,u,v} x[b,c,i+u,j+v] * w[i,j,o,c,u,v]
// x: [64,64,32,32] f32 ; w: [28,28,128,64,5,5] f32 (642 MB streamed once) ;
// out: [64,128,28,28] f32. Per-position GEMM M=64,N=128,K=1600, bf16 MFMA.
//
// Round-2 structure:
//  1) pack_x: gather x (coalesced reads) -> P[g][cb][b][kc] bf16 in d_ws (153 MB),
//     laid out exactly in the main kernel's LDS staging order.
//  2) lconv_main: grid 1568 = (784 positions x split-K/2). Double-buffered
//     global_load_lds staging of P chunks (20 KB linear copy, 1 barrier/chunk),
//     weights streamed direct-to-reg (nontemporal dwordx4), fp32 atomicAdd
//     epilogue onto memset-zeroed out.
// Fallback to round-1 kernel if ws_size too small.

typedef __attribute__((ext_vector_type(8))) short bf16x8;
typedef __attribute__((ext_vector_type(4))) float f32x4;
typedef unsigned int u32;
typedef unsigned short u16;

__device__ __forceinline__ u16 f2bf(float f) {
    u32 u = __float_as_uint(f);
    u = (u + 0x7fffu + ((u >> 16) & 1u)) >> 16;   // RNE
    return (u16)u;
}

// ---------------- pack kernel ----------------
// P[g<784][cb<10][b<64][kc<160] bf16, k = cb*160+kc = c*25 + u*5 + v
// Block = (b, cg) : stages x[b, 8c-slab] to LDS (coalesced), writes P linear.
__global__ __launch_bounds__(256) void pack_x(const float* __restrict__ x,
                                              u16* __restrict__ P) {
    const int b  = blockIdx.x >> 3;
    const int cg = blockIdx.x & 7;            // c in [8*cg, 8*cg+8)
    const int t  = threadIdx.x;
    __shared__ u16 Xs[8 * 1024];              // [c_local][h][w] bf16, 16 KB

    const float* xb = x + b * 65536 + cg * 8192;
#pragma unroll
    for (int r = 0; r < 8; ++r) {
        int off = r * 1024 + t * 4;
        f32x4 v = *(const f32x4*)(xb + off);
        *(u32*)&Xs[off]     = (u32)f2bf(v[0]) | ((u32)f2bf(v[1]) << 16);
        *(u32*)&Xs[off + 2] = (u32)f2bf(v[2]) | ((u32)f2bf(v[3]) << 16);
    }
    __syncthreads();

    // This block owns k-slice [cg*200, cg*200+200) for all 784 g: 78400 dwords.
    u32* Pd = (u32*)P;
    for (int idx = t; idx < 78400; idx += 256) {
        int g   = idx / 100;
        int rem = idx - g * 100;
        int i = g / 28;
        int j = g - i * 28;
        int e0 = rem * 2;
        int c0 = e0 / 25, r0 = e0 - c0 * 25, u0 = r0 / 5, v0 = r0 - u0 * 5;
        int e1 = e0 + 1;
        int c1 = e1 / 25, r1 = e1 - c1 * 25, u1 = r1 / 5, v1 = r1 - u1 * 5;
        u16 a0 = Xs[c0 * 1024 + (i + u0) * 32 + (j + v0)];
        u16 a1 = Xs[c1 * 1024 + (i + u1) * 32 + (j + v1)];
        int kg = cg * 200 + e0;               // even; pair never straddles a chunk
        int cb = kg / 160;
        int kc = kg - cb * 160;
        Pd[((g * 10 + cb) * 64 + b) * 80 + (kc >> 1)] = (u32)a0 | ((u32)a1 << 16);
    }
}

// ---------------- main GEMM kernel ----------------
__device__ __forceinline__ void glds16(const void* g, void* l) {
    __builtin_amdgcn_global_load_lds(
        (const __attribute__((address_space(1))) u32*)g,
        (__attribute__((address_space(3))) u32*)l, 16, 0, 0);
}

__global__ __launch_bounds__(256, 4) void lconv_main(const float* __restrict__ wgt,
                                                     const u16* __restrict__ P,
                                                     float* __restrict__ out) {
    constexpr int KC = 160;                   // 5 MFMA k-steps per chunk
    __shared__ u16 As[2][64 * KC];            // 2 x 20480 B

    const int bx = blockIdx.x;
    const int s  = bx & 1;                    // K-half
    const int bq = bx >> 1;
    const int g  = (bq & 7) * 98 + (bq >> 3); // XCD swizzle

    const int t = threadIdx.x, lane = t & 63, wv = t >> 6;
    const int l15 = lane & 15, quad = lane >> 4;

    const u16*   Pg = P + (size_t)g * 102400 + (size_t)s * 5 * 10240;
    const float* wg = wgt + (size_t)g * 204800 + (size_t)s * 800;

    f32x4 acc[4][2];
#pragma unroll
    for (int mt = 0; mt < 4; ++mt)
#pragma unroll
        for (int nt = 0; nt < 2; ++nt)
            acc[mt][nt] = (f32x4)0.f;

    // chunk staging: 20480 B linear copy, 5 glds16 per wave
    auto stage = [&](int cb, int buf) {
        const char* src = (const char*)(Pg + cb * 10240);
        char* dst = (char*)&As[buf][0];
#pragma unroll
        for (int r = 0; r < 5; ++r) {
            int off = wv * 1024 + r * 4096;
            glds16(src + off + lane * 16, dst + off);
        }
    };

    stage(0, 0);
    __syncthreads();

    for (int cb = 0; cb < 5; ++cb) {
        if (cb < 4) stage(cb + 1, (cb + 1) & 1);
        const u16*   A  = As[cb & 1];
        const float* wc = wg + cb * 160;
#pragma unroll
        for (int ks = 0; ks < 5; ++ks) {
            bf16x8 bfr[2];
#pragma unroll
            for (int nt = 0; nt < 2; ++nt) {
                const int o = wv * 32 + nt * 16 + l15;
                const float* wp = wc + (size_t)o * 1600 + ks * 32 + quad * 8;
                f32x4 w0 = __builtin_nontemporal_load((const f32x4*)wp);
                f32x4 w1 = __builtin_nontemporal_load((const f32x4*)wp + 1);
                bf16x8 bv;
                bv[0] = (short)f2bf(w0[0]); bv[1] = (short)f2bf(w0[1]);
                bv[2] = (short)f2bf(w0[2]); bv[3] = (short)f2bf(w0[3]);
                bv[4] = (short)f2bf(w1[0]); bv[5] = (short)f2bf(w1[1]);
                bv[6] = (short)f2bf(w1[2]); bv[7] = (short)f2bf(w1[3]);
                bfr[nt] = bv;
            }
#pragma unroll
            for (int mt = 0; mt < 4; ++mt) {
                bf16x8 av = *(const bf16x8*)&A[(mt * 16 + l15) * KC + ks * 32 + quad * 8];
#pragma unroll
                for (int nt = 0; nt < 2; ++nt)
                    acc[mt][nt] = __builtin_amdgcn_mfma_f32_16x16x32_bf16(
                        av, bfr[nt], acc[mt][nt], 0, 0, 0);
            }
        }
        if (cb < 4) __syncthreads();
    }

    // epilogue: D[m=quad*4+r][n=l15]; two K-halves combine via atomicAdd
#pragma unroll
    for (int mt = 0; mt < 4; ++mt)
#pragma unroll
        for (int nt = 0; nt < 2; ++nt) {
            const int o = wv * 32 + nt * 16 + l15;
#pragma unroll
            for (int r = 0; r < 4; ++r) {
                const int b = mt * 16 + quad * 4 + r;
                atomicAdd(&out[((size_t)b * 128 + o) * 784 + g], acc[mt][nt][r]);
            }
        }
}

// ---------------- round-1 fallback (ws too small) ----------------
__global__ __launch_bounds__(256, 3) void lconv_mfma(
    const float* __restrict__ x,
    const float* __restrict__ wgt,
    float* __restrict__ out)
{
    constexpr int K = 1600, KC = 64, LDK = KC + 8, O = 128, POS = 784;
    __shared__ u16 As[64][LDK];
    const int bx = blockIdx.x;
    const int g = (bx & 7) * 98 + (bx >> 3);
    const int i = g / 28, j = g - i * 28;
    const int t = threadIdx.x, lane = t & 63, wv = t >> 6;
    const int l15 = lane & 15, quad = lane >> 4;
    const float* xbase = x + i * 32 + j;
    const int sb = t >> 2, sk = (t & 3) * 16;
    const float* xrow = xbase + sb * 65536;
    const float* wpos = wgt + (size_t)g * (size_t)(O * K);
    f32x4 acc[4][2];
#pragma unroll
    for (int mt = 0; mt < 4; ++mt)
#pragma unroll
        for (int nt = 0; nt < 2; ++nt) acc[mt][nt] = (f32x4)0.f;
    for (int kb = 0; kb < K; kb += KC) {
        u32 pk[8];
#pragma unroll
        for (int e = 0; e < 16; e += 2) {
            int k0 = kb + sk + e;
            int c0 = k0 / 25, r0 = k0 - 25 * c0, u0 = r0 / 5, v0 = r0 - 5 * u0;
            int k1 = k0 + 1;
            int c1 = k1 / 25, r1 = k1 - 25 * c1, u1 = r1 / 5, v1 = r1 - 5 * u1;
            float f0 = xrow[c0 * 1024 + u0 * 32 + v0];
            float f1 = xrow[c1 * 1024 + u1 * 32 + v1];
            pk[e >> 1] = (u32)f2bf(f0) | ((u32)f2bf(f1) << 16);
        }
        *(uint4*)&As[sb][sk]     = make_uint4(pk[0], pk[1], pk[2], pk[3]);
        *(uint4*)&As[sb][sk + 8] = make_uint4(pk[4], pk[5], pk[6], pk[7]);
        __syncthreads();
#pragma unroll
        for (int kk = 0; kk < 2; ++kk) {
            bf16x8 bfr[2];
#pragma unroll
            for (int nt = 0; nt < 2; ++nt) {
                const int o = wv * 32 + nt * 16 + l15;
                const float* wp = wpos + (size_t)o * K + (kb + kk * 32 + quad * 8);
                f32x4 w0 = *(const f32x4*)wp;
                f32x4 w1 = *(const f32x4*)(wp + 4);
                bf16x8 bv;
                bv[0] = (short)f2bf(w0[0]); bv[1] = (short)f2bf(w0[1]);
                bv[2] = (short)f2bf(w0[2]); bv[3] = (short)f2bf(w0[3]);
                bv[4] = (short)f2bf(w1[0]); bv[5] = (short)f2bf(w1[1]);
                bv[6] = (short)f2bf(w1[2]); bv[7] = (short)f2bf(w1[3]);
                bfr[nt] = bv;
            }
#pragma unroll
            for (int mt = 0; mt < 4; ++mt) {
                bf16x8 av = *(const bf16x8*)&As[mt * 16 + l15][kk * 32 + quad * 8];
#pragma unroll
                for (int nt = 0; nt < 2; ++nt)
                    acc[mt][nt] = __builtin_amdgcn_mfma_f32_16x16x32_bf16(
                        av, bfr[nt], acc[mt][nt], 0, 0, 0);
            }
        }
        __syncthreads();
    }
#pragma unroll
    for (int mt = 0; mt < 4; ++mt)
#pragma unroll
        for (int nt = 0; nt < 2; ++nt) {
            const int o = wv * 32 + nt * 16 + l15;
#pragma unroll
            for (int r = 0; r < 4; ++r) {
                const int b = mt * 16 + quad * 4 + r;
                out[((size_t)b * O + o) * POS + g] = acc[mt][nt][r];
            }
        }
}

extern "C" void kernel_launch(void* const* d_in, const int* in_sizes, int n_in,
                              void* d_out, int out_size, void* d_ws, size_t ws_size,
                              hipStream_t stream) {
    const float* x   = (const float*)d_in[0];
    const float* wgt = (const float*)d_in[1];
    float* out       = (float*)d_out;
    const size_t PBYTES = 784ull * 10 * 64 * 160 * 2;   // 160,563,200 B
    if (ws_size >= PBYTES) {
        hipMemsetAsync(d_out, 0, (size_t)out_size * sizeof(float), stream);
        pack_x<<<512, 256, 0, stream>>>(x, (u16*)d_ws);
        lconv_main<<<1568, 256, 0, stream>>>(wgt, (const u16*)d_ws, out);
    } else {
        lconv_mfma<<<784, 256, 0, stream>>>(x, wgt, out);
    }
}

// Round 3
// 1070.575 us; speedup vs baseline: 1.3807x; 1.3807x over previous
//
#include <hip/hip_runtime.h>

// LocalConvolution: out[b,o,i,j] = sum_{c,u,v} x[b,c,i+u,j+v] * w[i,j,o,c,u,v]
// x: [64,64,32,32] f32 ; w: [28,28,128,64,5,5] f32 (642 MB streamed once) ;
// out: [64,128,28,28] f32. Per-position GEMM M=64(b), N=128(o), K=1600, bf16 MFMA.
//
// Round-3:
//  pack_x: grid 7840 = (784 g x 10 k-chunks). Thread = (b, quarter): 40 scalar
//          x reads (16 MB tensor, L2/L3-hot), pack bf16, 80 B coalesced write.
//          -> P[g][cb][b][kc] in d_ws (153 MB), main kernel's exact LDS order.
//  lconv_main: grid 1568 = 784 g x 2 o-halves (split-N: plain stores, no atomics).
//          Per chunk: ALL 10 weight dwordx4 hoisted to a register array (keeps
//          ~15 KB/wave in flight -> BW-bound not latency-bound), glds16 double-
//          buffered A staging, 20 MFMA. Swizzle: s-pair + g-neighbors same XCD.

typedef __attribute__((ext_vector_type(8))) short bf16x8;
typedef __attribute__((ext_vector_type(4))) float f32x4;
typedef unsigned int u32;
typedef unsigned short u16;

__device__ __forceinline__ u16 f2bf(float f) {
    u32 u = __float_as_uint(f);
    u = (u + 0x7fffu + ((u >> 16) & 1u)) >> 16;   // RNE
    return (u16)u;
}

// ---------------- pack kernel ----------------
// P[g<784][cb<10][b<64][kc<160] bf16 ; k = cb*160+kc = c*25 + u*5 + v
__global__ __launch_bounds__(256) void pack_x(const float* __restrict__ x,
                                              u16* __restrict__ P) {
    const int blk = blockIdx.x;
    const int g  = blk / 10;
    const int cb = blk - g * 10;
    const int i = g / 28;
    const int j = g - i * 28;
    const int t = threadIdx.x;
    const int b = t >> 2;
    const int q = t & 3;

    const float* xb = x + b * 65536 + i * 32 + j;
    const unsigned kbase = (unsigned)(cb * 160 + q * 40);

    u16 buf[40];
#pragma unroll
    for (unsigned e = 0; e < 40; ++e) {
        unsigned k = kbase + e;
        unsigned c = k / 25u;
        unsigned r = k - c * 25u;
        unsigned u = r / 5u;
        unsigned v = r - u * 5u;
        buf[e] = f2bf(xb[c * 1024 + u * 32 + v]);
    }
    u16* Pr = P + (((size_t)g * 10 + cb) * 64 + b) * 160 + q * 40;
#pragma unroll
    for (int r = 0; r < 5; ++r)
        *(uint4*)(Pr + r * 8) = *(const uint4*)&buf[r * 8];
}

// ---------------- main GEMM kernel ----------------
__device__ __forceinline__ void glds16(const void* g, void* l) {
    __builtin_amdgcn_global_load_lds(
        (const __attribute__((address_space(1))) u32*)g,
        (__attribute__((address_space(3))) u32*)l, 16, 0, 0);
}

__global__ __launch_bounds__(256, 3) void lconv_main(const float* __restrict__ wgt,
                                                     const u16* __restrict__ P,
                                                     float* __restrict__ out) {
    constexpr int KC = 160;                    // 5 MFMA k-steps per chunk
    __shared__ u16 As[2][64 * KC];             // 2 x 20480 B

    const int bx = blockIdx.x;
    // s-pair (o-halves of same g) and g-neighbors land on the same XCD:
    const int s  = (bx >> 3) & 1;              // o-half
    const int bq = (bx & 7) | ((bx >> 4) << 3);
    const int g  = (bq & 7) * 98 + (bq >> 3);  // XCD swizzle over positions

    const int t = threadIdx.x, lane = t & 63, wv = t >> 6;
    const int l15 = lane & 15, quad = lane >> 4;

    const u16*   Pg = P + (size_t)g * 102400;                    // [10][64][160]
    const float* wg = wgt + (size_t)g * 204800 + (size_t)(s * 64) * 1600;
    // this wave's weight row (o' = wv*16 + l15), k-sub offset quad*8
    const float* wrow = wg + (size_t)(wv * 16 + l15) * 1600 + quad * 8;

    f32x4 acc[4];
#pragma unroll
    for (int mt = 0; mt < 4; ++mt) acc[mt] = (f32x4)0.f;

    auto stage = [&](int cb, int buf) {
        const char* src = (const char*)(Pg + cb * 10240);
        char* dst = (char*)&As[buf][0];
#pragma unroll
        for (int r = 0; r < 5; ++r) {
            int off = wv * 1024 + r * 4096;
            glds16(src + off + lane * 16, dst + off);
        }
    };

    stage(0, 0);
    __syncthreads();

    for (int cb = 0; cb < 10; ++cb) {
        // ---- hoist ALL weight loads for this chunk (10 dwordx4 in flight) ----
        const float* wc = wrow + cb * 160;
        f32x4 wr[10];
#pragma unroll
        for (int ks = 0; ks < 5; ++ks) {
            wr[2 * ks]     = *(const f32x4*)(wc + ks * 32);
            wr[2 * ks + 1] = *(const f32x4*)(wc + ks * 32 + 4);
        }
        if (cb < 9) stage(cb + 1, (cb + 1) & 1);

        const u16* A = As[cb & 1];
#pragma unroll
        for (int ks = 0; ks < 5; ++ks) {
            f32x4 w0 = wr[2 * ks], w1 = wr[2 * ks + 1];
            bf16x8 bv;
            bv[0] = (short)f2bf(w0[0]); bv[1] = (short)f2bf(w0[1]);
            bv[2] = (short)f2bf(w0[2]); bv[3] = (short)f2bf(w0[3]);
            bv[4] = (short)f2bf(w1[0]); bv[5] = (short)f2bf(w1[1]);
            bv[6] = (short)f2bf(w1[2]); bv[7] = (short)f2bf(w1[3]);
#pragma unroll
            for (int mt = 0; mt < 4; ++mt) {
                bf16x8 av = *(const bf16x8*)&A[(mt * 16 + l15) * KC + ks * 32 + quad * 8];
                acc[mt] = __builtin_amdgcn_mfma_f32_16x16x32_bf16(av, bv, acc[mt], 0, 0, 0);
            }
        }
        if (cb < 9) __syncthreads();
    }

    // ---- epilogue: D[m=quad*4+r][n=l15] -> out[b][o][g], plain stores ----
    const int o = s * 64 + wv * 16 + l15;
#pragma unroll
    for (int mt = 0; mt < 4; ++mt)
#pragma unroll
        for (int r = 0; r < 4; ++r) {
            const int b = mt * 16 + quad * 4 + r;
            out[((size_t)b * 128 + o) * 784 + g] = acc[mt][r];
        }
}

// ---------------- round-1 fallback (ws too small) ----------------
__global__ __launch_bounds__(256, 3) void lconv_mfma(
    const float* __restrict__ x,
    const float* __restrict__ wgt,
    float* __restrict__ out)
{
    constexpr int K = 1600, KC = 64, LDK = KC + 8, O = 128, POS = 784;
    __shared__ u16 As[64][LDK];
    const int bx = blockIdx.x;
    const int g = (bx & 7) * 98 + (bx >> 3);
    const int i = g / 28, j = g - i * 28;
    const int t = threadIdx.x, lane = t & 63, wv = t >> 6;
    const int l15 = lane & 15, quad = lane >> 4;
    const float* xbase = x + i * 32 + j;
    const int sb = t >> 2, sk = (t & 3) * 16;
    const float* xrow = xbase + sb * 65536;
    const float* wpos = wgt + (size_t)g * (size_t)(O * K);
    f32x4 acc[4][2];
#pragma unroll
    for (int mt = 0; mt < 4; ++mt)
#pragma unroll
        for (int nt = 0; nt < 2; ++nt) acc[mt][nt] = (f32x4)0.f;
    for (int kb = 0; kb < K; kb += KC) {
        u32 pk[8];
#pragma unroll
        for (int e = 0; e < 16; e += 2) {
            int k0 = kb + sk + e;
            int c0 = k0 / 25, r0 = k0 - 25 * c0, u0 = r0 / 5, v0 = r0 - 5 * u0;
            int k1 = k0 + 1;
            int c1 = k1 / 25, r1 = k1 - 25 * c1, u1 = r1 / 5, v1 = r1 - 5 * u1;
            float f0 = xrow[c0 * 1024 + u0 * 32 + v0];
            float f1 = xrow[c1 * 1024 + u1 * 32 + v1];
            pk[e >> 1] = (u32)f2bf(f0) | ((u32)f2bf(f1) << 16);
        }
        *(uint4*)&As[sb][sk]     = make_uint4(pk[0], pk[1], pk[2], pk[3]);
        *(uint4*)&As[sb][sk + 8] = make_uint4(pk[4], pk[5], pk[6], pk[7]);
        __syncthreads();
#pragma unroll
        for (int kk = 0; kk < 2; ++kk) {
            bf16x8 bfr[2];
#pragma unroll
            for (int nt = 0; nt < 2; ++nt) {
                const int o = wv * 32 + nt * 16 + l15;
                const float* wp = wpos + (size_t)o * K + (kb + kk * 32 + quad * 8);
                f32x4 w0 = *(const f32x4*)wp;
                f32x4 w1 = *(const f32x4*)(wp + 4);
                bf16x8 bv;
                bv[0] = (short)f2bf(w0[0]); bv[1] = (short)f2bf(w0[1]);
                bv[2] = (short)f2bf(w0[2]); bv[3] = (short)f2bf(w0[3]);
                bv[4] = (short)f2bf(w1[0]); bv[5] = (short)f2bf(w1[1]);
                bv[6] = (short)f2bf(w1[2]); bv[7] = (short)f2bf(w1[3]);
                bfr[nt] = bv;
            }
#pragma unroll
            for (int mt = 0; mt < 4; ++mt) {
                bf16x8 av = *(const bf16x8*)&As[mt * 16 + l15][kk * 32 + quad * 8];
#pragma unroll
                for (int nt = 0; nt < 2; ++nt)
                    acc[mt][nt] = __builtin_amdgcn_mfma_f32_16x16x32_bf16(
                        av, bfr[nt], acc[mt][nt], 0, 0, 0);
            }
        }
        __syncthreads();
    }
#pragma unroll
    for (int mt = 0; mt < 4; ++mt)
#pragma unroll
        for (int nt = 0; nt < 2; ++nt) {
            const int o = wv * 32 + nt * 16 + l15;
#pragma unroll
            for (int r = 0; r < 4; ++r) {
                const int b = mt * 16 + quad * 4 + r;
                out[((size_t)b * O + o) * POS + g] = acc[mt][nt][r];
            }
        }
}

extern "C" void kernel_launch(void* const* d_in, const int* in_sizes, int n_in,
                              void* d_out, int out_size, void* d_ws, size_t ws_size,
                              hipStream_t stream) {
    const float* x   = (const float*)d_in[0];
    const float* wgt = (const float*)d_in[1];
    float* out       = (float*)d_out;
    const size_t PBYTES = 784ull * 10 * 64 * 160 * 2;   // 160,563,200 B
    if (ws_size >= PBYTES) {
        pack_x<<<7840, 256, 0, stream>>>(x, (u16*)d_ws);
        lconv_main<<<1568, 256, 0, stream>>>(wgt, (const u16*)d_ws, out);
    } else {
        lconv_mfma<<<784, 256, 0, stream>>>(x, wgt, out);
    }
}